// Round 10
// baseline (4898.980 us; speedup 1.0000x reference)
//
#include <hip/hip_runtime.h>
#include <math.h>

// ---------------- problem constants ----------------
#define B_    128
#define T_    64
#define INX   512
#define CTRL  512
#define NN    128
#define MMM   128
#define RR    4
#define LLh   134
#define NOUT  926
#define NWG   256
#define NTHR  1024

// Dataflow kernel: 256 WGs x 1024 threads, 1 WG/CU (static LDS ~107KB).
// Roles per WG:
//   B-GEMM tile: rowgB = wg>>5 (16 batches), colgB = wg&31 (16 cols of Wc2)
//   C-GEMM tile: wg<232: rowgC = wg/29, colgC = wg%29 (32 cols of Wk)
//   D (heads+Mem): wg<128 owns batch wg; Mem persistent in LDS
// Sync: monotonic per-rowgroup counters in d_ws (relaxed agent atomics):
//   cntB[g] += 32/step, cntC[g] += 29/step, cntD[g] += 16/step (+16 init)
//   B(t) waits cntD[rowgB] >= 16(t+1); C(t) waits cntB[rowgC] >= 32(t+1);
//   D(t) waits cntC[b>>4]  >= 29(t+1).
// Race-freedom: every producer's overwrite is gated (transitively via the
// counter chain) behind all consumers' reads of the previous value.

struct __align__(16) SMX {
  float Mem[NN][129];    // 66,048 B (owners only; persistent)
  float rw[RR][NN];      //  2,048
  float ww[NN];          //    512
  float instr[928];      //  3,712
  float invn[MMM];       //    512
  float red[1024];       //  4,096  (B/C k-split reduce; D norm partials)
  float stage[16][512];  // 32,768  (B: rv tile; C: out tile)
};                        // ~109.7 KB -> 1 WG/CU guaranteed

// ---------------- flag helpers (relaxed polls, sparse acquire) ----------------
__device__ __forceinline__ void spin_ge(int* p, int target) {
  int it = 0;
  while (__hip_atomic_load(p, __ATOMIC_RELAXED, __HIP_MEMORY_SCOPE_AGENT) < target) {
    __builtin_amdgcn_s_sleep(8);
    if ((++it & 15) == 0) __builtin_amdgcn_fence(__ATOMIC_ACQUIRE, "agent");
    if (it > (1 << 18)) break;   // safety: wrong answer beats hang
  }
  __builtin_amdgcn_fence(__ATOMIC_ACQUIRE, "agent");
}
__device__ __forceinline__ void arrive(int* p) {
  // caller must __syncthreads() first (drains all waves' stores to L2)
  __builtin_amdgcn_fence(__ATOMIC_RELEASE, "agent");
  __hip_atomic_fetch_add(p, 1, __ATOMIC_RELAXED, __HIP_MEMORY_SCOPE_AGENT);
}

// ---------------- wave reductions ----------------
__device__ __forceinline__ float wsum64(float v) {
  #pragma unroll
  for (int m = 32; m >= 1; m >>= 1) v += __shfl_xor(v, m);
  return v;
}
__device__ __forceinline__ float wmax64(float v) {
  #pragma unroll
  for (int m = 32; m >= 1; m >>= 1) v = fmaxf(v, __shfl_xor(v, m));
  return v;
}

// ---------------- precompute: d_out = X(8192x512) @ Wc[0:512,:] + bc ----------------
__global__ __launch_bounds__(256) void pre_mm(const float* __restrict__ X,
                                              const float* __restrict__ Wc,
                                              const float* __restrict__ bc,
                                              float* __restrict__ out) {
  __shared__ float Xs[16][68];
  __shared__ float Ws[16][64];
  const int wg = blockIdx.x;
  const int r0 = (wg >> 3) * 64, c0 = (wg & 7) * 64;
  const int tid = threadIdx.x;
  const int ti = tid >> 4, tj = tid & 15;
  float acc[4][4] = {};
  for (int kk = 0; kk < 512; kk += 16) {
    __syncthreads();
    for (int e = tid; e < 1024; e += 256) {
      int i = e >> 4, k = e & 15;
      Xs[k][i] = X[(size_t)(r0 + i) * 512 + kk + k];
    }
    for (int e = tid; e < 1024; e += 256) {
      int k = e >> 6, jx = e & 63;
      Ws[k][jx] = Wc[(size_t)(kk + k) * CTRL + c0 + jx];
    }
    __syncthreads();
    #pragma unroll
    for (int k = 0; k < 16; ++k) {
      float a0 = Xs[k][ti*4+0], a1 = Xs[k][ti*4+1], a2 = Xs[k][ti*4+2], a3 = Xs[k][ti*4+3];
      float b0 = Ws[k][tj*4+0], b1 = Ws[k][tj*4+1], b2 = Ws[k][tj*4+2], b3 = Ws[k][tj*4+3];
      acc[0][0]+=a0*b0; acc[0][1]+=a0*b1; acc[0][2]+=a0*b2; acc[0][3]+=a0*b3;
      acc[1][0]+=a1*b0; acc[1][1]+=a1*b1; acc[1][2]+=a1*b2; acc[1][3]+=a1*b3;
      acc[2][0]+=a2*b0; acc[2][1]+=a2*b1; acc[2][2]+=a2*b2; acc[2][3]+=a2*b3;
      acc[3][0]+=a3*b0; acc[3][1]+=a3*b1; acc[3][2]+=a3*b2; acc[3][3]+=a3*b3;
    }
  }
  #pragma unroll
  for (int i = 0; i < 4; ++i) {
    size_t o = (size_t)(r0 + ti*4 + i) * 512 + c0 + tj*4;
    float4 v = { acc[i][0] + bc[c0+tj*4+0], acc[i][1] + bc[c0+tj*4+1],
                 acc[i][2] + bc[c0+tj*4+2], acc[i][3] + bc[c0+tj*4+3] };
    *(float4*)&out[o] = v;
  }
}

// ---------------- one head task on one wave (round-7-proven, single batch) ----------
__device__ __forceinline__ void do_head(SMX& sm, int hd, int lane) {
  const int off = (hd < RR) ? hd * LLh : RR * LLh;
  const float* ins = sm.instr;
  const int n0 = lane, n1 = lane + 64;

  float k0 = ins[off + n0], k1 = ins[off + n1];
  float invk = rsqrtf(fmaxf(wsum64(k0 * k0 + k1 * k1), 1e-12f));
  float beta = expf(ins[off + 128]);
  float gg = 1.f / (1.f + expf(-ins[off + 129]));
  float s0 = ins[off + 130], s1 = ins[off + 131], s2 = ins[off + 132];
  float smx = fmaxf(s0, fmaxf(s1, s2));
  float e0 = expf(s0 - smx), e1 = expf(s1 - smx), e2 = expf(s2 - smx);
  float esm = e0 + e1 + e2; s0 = e0 / esm; s1 = e1 / esm; s2 = e2 / esm;
  float spx = ins[off + 133];
  float tt = ((spx > 20.f) ? spx : log1pf(expf(spx))) + 1.0f;

  float p0 = 0.f, p1 = 0.f;
  #pragma unroll 4
  for (int m = 0; m < 128; ++m) {
    float km = sm.invn[m] * ins[off + m];
    p0 += sm.Mem[n0][m] * km;
    p1 += sm.Mem[n1][m] * km;
  }
  float sim0 = p0 * invk * beta, sim1 = p1 * invk * beta;
  float mx = wmax64(fmaxf(sim0, sim1));
  float ev0 = expf(sim0 - mx), ev1 = expf(sim1 - mx);
  float es = wsum64(ev0 + ev1);
  float wold0 = (hd < RR) ? sm.rw[hd][n0] : sm.ww[n0];
  float wold1 = (hd < RR) ? sm.rw[hd][n1] : sm.ww[n1];
  float wi0 = gg * (ev0 / es) + (1.f - gg) * wold0;
  float wi1 = gg * (ev1 / es) + (1.f - gg) * wold1;

  int ls = (lane + 63) & 63;
  float A0 = __shfl(wi0, ls), A1 = __shfl(wi1, ls);
  float wprev0 = (lane == 0) ? A1 : A0;
  float wprev1 = (lane == 0) ? A0 : A1;
  int ln = (lane + 1) & 63;
  float B0 = __shfl(wi0, ln), B1 = __shfl(wi1, ln);
  float wnext0 = (lane == 63) ? B1 : B0;
  float wnext1 = (lane == 63) ? B0 : B1;

  float ws0 = s0 * wprev0 + s1 * wi0 + s2 * wnext0;
  float ws1 = s0 * wprev1 + s1 * wi1 + s2 * wnext1;
  float pv0 = powf(ws0, tt), pv1 = powf(ws1, tt);
  float inv = 1.f / (wsum64(pv0 + pv1) + 1e-12f);
  if (hd < RR) { sm.rw[hd][n0] = pv0 * inv; sm.rw[hd][n1] = pv1 * inv; }
  else         { sm.ww[n0]     = pv0 * inv; sm.ww[n1]     = pv1 * inv; }
}

// ---------------- dataflow kernel ----------------
__global__ __launch_bounds__(1024) void ntm3(const float* __restrict__ Wc,
                                             const float* __restrict__ Wk,
                                             const float* __restrict__ bk,
                                             float* __restrict__ out,
                                             float* __restrict__ instr_g,
                                             float* __restrict__ rv_g,
                                             int* __restrict__ cnt) {
  __shared__ SMX sm;
  const int wg = blockIdx.x, tid = threadIdx.x;
  const int lane = tid & 63, wv = tid >> 6;

  const int rowgB = wg >> 5, colgB = wg & 31;          // B: 8 x 32 grid
  const int hasC  = (wg < 232);
  const int rowgC = wg / 29, colgC = wg - rowgC * 29;  // C: 8 x 29 grid
  const int isOwner = (wg < B_);
  const int bD = wg;

  int* cntB = cnt;          // index g*16 (64B spacing)
  int* cntC = cnt + 128;
  int* cntD = cnt + 256;

  // ---- init: owners set up Mem/rw/ww in LDS, zero rv_g, then announce ----
  if (isOwner) {
    for (int e = tid; e < NN * MMM; e += NTHR) {
      int n = e >> 7;
      sm.Mem[n][e & 127] = (n == NN / 2) ? 1.0f : 0.0f;
    }
    for (int e = tid; e < RR * NN; e += NTHR) ((float*)sm.rw)[e] = 0.0f;
    if (tid < NN) sm.ww[tid] = 0.0f;
    if (tid < 512) rv_g[(size_t)bD * 512 + tid] = 0.0f;
    __syncthreads();                       // drains the rv stores
    if (tid == 0) arrive(&cntD[(bD >> 4) * 16]);
  }
  __syncthreads();

  for (int t = 0; t < T_; ++t) {
    // ===== phase B: out[b][t][:] = tanh(pre + rv @ Wc2), tile 16b x 16c =====
    if (tid == 0) spin_ge(&cntD[rowgB * 16], 16 * (t + 1));
    __syncthreads();
    {
      const int b0 = rowgB * 16, c0 = colgB * 16;
      // stage rv tile [16][512]
      for (int e = tid * 4; e < 8192; e += NTHR * 4) {
        int i = e >> 9, k = e & 511;
        *(float4*)&sm.stage[i][k] = *(const float4*)&rv_g[(size_t)(b0 + i) * 512 + k];
      }
      __syncthreads();
      const int kh = tid >> 8, i = (tid >> 4) & 15, jc = tid & 15;  // kh 0..3
      const float* wp = Wc + (size_t)(INX + kh * 128) * CTRL + c0 + jc;
      const float* rvrow = &sm.stage[i][kh * 128];
      float a = 0.f;
      for (int k8 = 0; k8 < 128; k8 += 8) {
        float w0 = wp[(size_t)(k8+0)*CTRL], w1 = wp[(size_t)(k8+1)*CTRL];
        float w2 = wp[(size_t)(k8+2)*CTRL], w3 = wp[(size_t)(k8+3)*CTRL];
        float w4 = wp[(size_t)(k8+4)*CTRL], w5 = wp[(size_t)(k8+5)*CTRL];
        float w6 = wp[(size_t)(k8+6)*CTRL], w7 = wp[(size_t)(k8+7)*CTRL];
        a += rvrow[k8+0]*w0 + rvrow[k8+1]*w1 + rvrow[k8+2]*w2 + rvrow[k8+3]*w3
           + rvrow[k8+4]*w4 + rvrow[k8+5]*w5 + rvrow[k8+6]*w6 + rvrow[k8+7]*w7;
      }
      if (kh > 0) sm.red[(kh - 1) * 256 + i * 16 + jc] = a;
      __syncthreads();
      if (kh == 0) {
        a += sm.red[i*16+jc] + sm.red[256 + i*16+jc] + sm.red[512 + i*16+jc];
        size_t o = ((size_t)(b0 + i) * T_ + t) * CTRL + c0 + jc;
        out[o] = tanhf(out[o] + a);
      }
    }
    __syncthreads();                       // drains out stores
    if (tid == 0) arrive(&cntB[rowgB * 16]);

    // ===== phase C: instr = out_t @ Wk + bk, tile 16b x 32c =====
    if (hasC) {
      if (tid == 0) spin_ge(&cntB[rowgC * 16], 32 * (t + 1));
      __syncthreads();
      const int b0 = rowgC * 16, c0 = colgC * 32;
      // stage out tile [16][512]
      for (int e = tid * 4; e < 8192; e += NTHR * 4) {
        int i = e >> 9, k = e & 511;
        *(float4*)&sm.stage[i][k] =
            *(const float4*)&out[((size_t)(b0 + i) * T_ + t) * CTRL + k];
      }
      __syncthreads();
      const int kh = tid >> 9, i = (tid >> 5) & 15, jc = tid & 31;  // kh 0..1
      const int col = c0 + jc;
      const int colw = (col < NOUT) ? col : (NOUT - 1);
      const float* wp = Wk + (size_t)(kh * 256) * NOUT + colw;
      const float* orow = &sm.stage[i][kh * 256];
      float a = 0.f;
      for (int k8 = 0; k8 < 256; k8 += 8) {
        float w0 = wp[(size_t)(k8+0)*NOUT], w1 = wp[(size_t)(k8+1)*NOUT];
        float w2 = wp[(size_t)(k8+2)*NOUT], w3 = wp[(size_t)(k8+3)*NOUT];
        float w4 = wp[(size_t)(k8+4)*NOUT], w5 = wp[(size_t)(k8+5)*NOUT];
        float w6 = wp[(size_t)(k8+6)*NOUT], w7 = wp[(size_t)(k8+7)*NOUT];
        a += orow[k8+0]*w0 + orow[k8+1]*w1 + orow[k8+2]*w2 + orow[k8+3]*w3
           + orow[k8+4]*w4 + orow[k8+5]*w5 + orow[k8+6]*w6 + orow[k8+7]*w7;
      }
      if (kh == 1) sm.red[i * 32 + jc] = a;
      __syncthreads();
      if (kh == 0 && col < NOUT) {
        a += sm.red[i * 32 + jc];
        instr_g[(size_t)(b0 + i) * 928 + col] = a + bk[col];
      }
      __syncthreads();                     // drains instr stores
      if (tid == 0) arrive(&cntC[rowgC * 16]);
    }

    // ===== phase D: owner batch heads + Mem update + rv =====
    if (isOwner) {
      if (tid == 0) spin_ge(&cntC[(bD >> 4) * 16], 29 * (t + 1));
      __syncthreads();
      // stage instr row
      if (tid < 928) sm.instr[tid] = instr_g[(size_t)bD * 928 + tid];
      __syncthreads();
      // column inv-norms over n (8-way split)
      {
        int m = tid & 127, h = tid >> 7;   // h 0..7
        float p = 0.f;
        #pragma unroll 8
        for (int q = 0; q < 16; ++q) { float v = sm.Mem[h*16+q][m]; p += v*v; }
        sm.red[tid] = p;
      }
      __syncthreads();
      if (tid < 128) {
        float s = sm.red[tid]       + sm.red[tid+128] + sm.red[tid+256] + sm.red[tid+384]
                + sm.red[tid+512]   + sm.red[tid+640] + sm.red[tid+768] + sm.red[tid+896];
        sm.invn[tid] = rsqrtf(fmaxf(s, 1e-12f));
      }
      __syncthreads();
      // 5 heads on waves 0..4
      if (wv < 5) do_head(sm, wv, lane);
      __syncthreads();
      // Mem update
      for (int e = tid; e < NN * MMM; e += NTHR) {
        int n = e >> 7, m = e & 127;
        float w = sm.ww[n];
        sm.Mem[n][m] = sm.Mem[n][m] * (1.f - w * sm.instr[670 + m])
                     + w * sm.instr[798 + m];
      }
      __syncthreads();
      // rv -> global
      if (tid < 512) {
        int m = tid & 127, r = tid >> 7;
        float acc = 0.f;
        const float* rwr = sm.rw[r];
        #pragma unroll 8
        for (int n = 0; n < NN; ++n) acc += sm.Mem[n][m] * rwr[n];
        rv_g[(size_t)bD * 512 + r * 128 + m] = acc;
      }
      __syncthreads();                     // drains rv stores
      if (tid == 0) arrive(&cntD[(bD >> 4) * 16]);
    }
  }
}

// ---------------- launch ----------------
extern "C" void kernel_launch(void* const* d_in, const int* in_sizes, int n_in,
                              void* d_out, int out_size, void* d_ws, size_t ws_size,
                              hipStream_t stream) {
  const float* x  = (const float*)d_in[0];
  const float* Wc = (const float*)d_in[1];
  const float* bc = (const float*)d_in[2];
  const float* Wk = (const float*)d_in[3];
  const float* bk = (const float*)d_in[4];
  float* out = (float*)d_out;

  char* ws = (char*)d_ws;
  int*   cnt     = (int*)ws;                                  // 384 ints, 64B-spaced
  float* instr_g = (float*)(ws + 2048);                       // 128*928*4 = 475,136 B
  float* rv_g    = (float*)(ws + 2048 + (size_t)B_*928*4);    // 128*512*4 = 262,144 B

  hipMemsetAsync(cnt, 0, 2048, stream);
  pre_mm<<<dim3(1024), dim3(256), 0, stream>>>(x, Wc, bc, out);
  ntm3<<<dim3(NWG), dim3(NTHR), 0, stream>>>(Wc, Wk, bk, out, instr_g, rv_g, cnt);
}